// Round 11
// baseline (117.520 us; speedup 1.0000x reference)
//
#include <hip/hip_runtime.h>
#include <math.h>

// B=2, C=1, H=W=2048, RADIUS=1, RK=3; J center plane is zeroed in setup.
namespace {
constexpr int H = 2048;
constexpr int W = 2048;
constexpr int NPIX = H * W;            // 2^22
constexpr int B = 2;
constexpr float DECf = 0.95f;
constexpr float OMDf = 1.0f - 0.95f;
}

using f4 = __attribute__((ext_vector_type(4))) float;

// R11 = full stack: batch-fused threads (J + rand_drop loaded ONCE into
// registers, used for both batches -> halves J's L2/L3-side service, the
// largest remaining cache-traffic term) + LDS halo exchange (R9; no scalar
// edge loads) + NT stores (R10; writes bypass L2/L3, -5% measured) + f4
// loads. R5/R6 established occupancy 17.5% vs 39% is time-neutral here, so
// the fusion's VGPR cost is safe. VMEM/px: 7.5 -> 4.9.
// Grid = (row, half) = 4096 blocks (%8==0), XCD-chunked bijective swizzle;
// adjacent rows on the same XCD-L2 for the 3-row stencil.
// LDS slot map per (batch,row): thread t publishes .x->2t, .w->2t+3;
// reads L=2t+1, R=2t+2; block-edge halo: slot1 <- [w0b-1], slot512 <-
// [w0b+1024] (wrap), loaded by lanes t<12 (1 VMEM instr, amortized).
// Numerics: decision path (tap-sum in tap order, delta_e, exp, compare) in
// f64 (passed 9x); EMA observables in f32 (passed R3-R10, absmax 0.0078).
__global__ __launch_bounds__(256) void ising_step_kernel(
    const float* __restrict__ x,      // (B, 2, H, W): s then b
    const float* __restrict__ obvs,   // (B, 4, H, W): e, e2, c, m
    const float* __restrict__ Jm,     // (1, 9, N)
    const float* __restrict__ rs,     // (B, 1, H, W)
    const float* __restrict__ rd,     // (1, 1, H, W)
    float* __restrict__ out)          // state (B,2,N) ++ obvs_out (B,4,N)
{
  __shared__ float lr[2][3][520];

  const int bid = blockIdx.x;
  const int u   = ((bid & 7) << 9) | (bid >> 3);   // 8 XCDs x 512 units
  const int h   = u >> 1;                          // [0,2048)
  const int t   = threadIdx.x;
  const int w0b = (u & 1) << 10;                   // block's first pixel col
  const int w0  = w0b | (t << 2);
  const int n0  = (h << 11) | w0;

  const int hm = (h - 1) & (H - 1);
  const int hp = (h + 1) & (H - 1);

  const float* rowp_[2][3];
  #pragma unroll
  for (int bi = 0; bi < 2; ++bi) {
    const float* sb = x + (size_t)bi * 2 * NPIX;
    rowp_[bi][0] = sb + (size_t)hm * W;
    rowp_[bi][1] = sb + (size_t)h  * W;
    rowp_[bi][2] = sb + (size_t)hp * W;
  }

  // ---- s-row loads first (LDS exchange depends only on these) ----
  f4 vrow[2][3];
  #pragma unroll
  for (int bi = 0; bi < 2; ++bi)
    #pragma unroll
    for (int r = 0; r < 3; ++r)
      vrow[bi][r] = *(const f4*)(rowp_[bi][r] + w0);

  // ---- batch-shared loads: 8 J planes + rand_drop, registers, used 2x ----
  f4 jv[8];
  #pragma unroll
  for (int k = 0; k < 8; ++k) {
    const int kk = (k < 4) ? k : (k + 1);   // skip zeroed center plane
    jv[k] = *(const f4*)(Jm + (size_t)kk * NPIX + n0);
  }
  const f4 dv = *(const f4*)(rd + n0);

  // ---- per-batch streams ----
  f4 bv[2], ev[2], e2v[2], cv[2], mv[2], rv[2];
  #pragma unroll
  for (int bi = 0; bi < 2; ++bi) {
    const float* sb = x + (size_t)bi * 2 * NPIX;
    bv[bi] = *(const f4*)(sb + (size_t)NPIX + n0);
    const float* ob = obvs + (size_t)bi * 4 * NPIX + n0;
    ev[bi]  = *(const f4*)(ob);
    e2v[bi] = *(const f4*)(ob + (size_t)NPIX);
    cv[bi]  = *(const f4*)(ob + 2 * (size_t)NPIX);
    mv[bi]  = *(const f4*)(ob + 3 * (size_t)NPIX);
    rv[bi]  = *(const f4*)(rs + (size_t)bi * NPIX + n0);
  }

  // ---- LDS edge exchange (both batches) ----
  #pragma unroll
  for (int bi = 0; bi < 2; ++bi)
    #pragma unroll
    for (int r = 0; r < 3; ++r) {
      lr[bi][r][2 * t]     = vrow[bi][r].x;
      lr[bi][r][2 * t + 3] = vrow[bi][r].w;
    }
  if (t < 12) {
    const int bsel = t / 6;
    const int rem  = t % 6;
    const int r    = rem >> 1;
    const int side = rem & 1;
    const float* rp = rowp_[bsel][r];
    const int wsrc = side ? ((w0b + 1024) & (W - 1)) : ((w0b - 1) & (W - 1));
    lr[bsel][r][side ? 512 : 1] = rp[wsrc];
  }
  __syncthreads();

  // ---- compute + NT store per batch ----
  #pragma unroll
  for (int bi = 0; bi < 2; ++bi) {
    const float Lm = lr[bi][0][2 * t + 1], Rm = lr[bi][0][2 * t + 2];
    const float Lc = lr[bi][1][2 * t + 1], Rc = lr[bi][1][2 * t + 2];
    const float Lp = lr[bi][2][2 * t + 1], Rp = lr[bi][2][2 * t + 2];
    const f4 vm = vrow[bi][0], vc = vrow[bi][1], vp = vrow[bi][2];
    const float am[6] = {Lm, vm.x, vm.y, vm.z, vm.w, Rm};
    const float ac[6] = {Lc, vc.x, vc.y, vc.z, vc.w, Rc};
    const float ap[6] = {Lp, vp.x, vp.y, vp.z, vp.w, Rp};
    const float bq[4]  = {bv[bi].x, bv[bi].y, bv[bi].z, bv[bi].w};
    const float eq[4]  = {ev[bi].x, ev[bi].y, ev[bi].z, ev[bi].w};
    const float e2q[4] = {e2v[bi].x, e2v[bi].y, e2v[bi].z, e2v[bi].w};
    const float cq[4]  = {cv[bi].x, cv[bi].y, cv[bi].z, cv[bi].w};
    const float mq[4]  = {mv[bi].x, mv[bi].y, mv[bi].z, mv[bi].w};
    const float rsq[4] = {rv[bi].x, rv[bi].y, rv[bi].z, rv[bi].w};
    const float rdq[4] = {dv.x, dv.y, dv.z, dv.w};

    float so[4], eo[4], e2o[4], co[4], mo[4];
    #pragma unroll
    for (int tt = 0; tt < 4; ++tt) {
      // decision-critical path in f64, reference tap order
      const double sum =
          (double)jv[0][tt] * am[tt]     + (double)jv[1][tt] * am[tt + 1] +
          (double)jv[2][tt] * am[tt + 2] + (double)jv[3][tt] * ac[tt]     +
          (double)jv[4][tt] * ac[tt + 2] + (double)jv[5][tt] * ap[tt]     +
          (double)jv[6][tt] * ap[tt + 1] + (double)jv[7][tt] * ap[tt + 2];
      const float sf  = ac[tt + 1];
      const double s  = (double)sf;
      const double de = 2.0 * s * sum;
      const double p  = (de <= 0.0) ? 1.0 : exp(-de * (double)bq[tt]);
      const bool acc  = ((double)rsq[tt] < p) && (rdq[tt] > 0.5f);
      // observables in f32
      const float E   = (float)(-s * sum);
      const float bf  = bq[tt];
      const float en  = DECf * eq[tt]  + OMDf * E;
      const float e2n = DECf * e2q[tt] + OMDf * E * E;
      const float cn  = DECf * cq[tt]  + OMDf * (e2n - en * en) * bf * bf;
      const float mn  = DECf * mq[tt]  + OMDf * sf;
      so[tt]  = acc ? -sf : sf;
      eo[tt]  = en;
      e2o[tt] = e2n;
      co[tt]  = cn;
      mo[tt]  = mn;
    }

    float* st = out + (size_t)bi * 2 * NPIX;
    float* oo = out + (size_t)B * 2 * NPIX + (size_t)bi * 4 * NPIX;
    __builtin_nontemporal_store((f4){so[0], so[1], so[2], so[3]}, (f4*)(st + n0));
    __builtin_nontemporal_store(bv[bi], (f4*)(st + (size_t)NPIX + n0));
    __builtin_nontemporal_store((f4){eo[0], eo[1], eo[2], eo[3]}, (f4*)(oo + n0));
    __builtin_nontemporal_store((f4){e2o[0], e2o[1], e2o[2], e2o[3]},
                                (f4*)(oo + (size_t)NPIX + n0));
    __builtin_nontemporal_store((f4){co[0], co[1], co[2], co[3]},
                                (f4*)(oo + 2 * (size_t)NPIX + n0));
    __builtin_nontemporal_store((f4){mo[0], mo[1], mo[2], mo[3]},
                                (f4*)(oo + 3 * (size_t)NPIX + n0));
  }
}

extern "C" void kernel_launch(void* const* d_in, const int* in_sizes, int n_in,
                              void* d_out, int out_size, void* d_ws, size_t ws_size,
                              hipStream_t stream) {
  const float* x    = (const float*)d_in[0];
  const float* obvs = (const float*)d_in[1];
  const float* Jm   = (const float*)d_in[2];
  const float* rs   = (const float*)d_in[3];
  const float* rd   = (const float*)d_in[4];
  float* out = (float*)d_out;

  constexpr int grid = H * 2;   // 4096 (row, half) blocks, both batches each
  ising_step_kernel<<<grid, 256, 0, stream>>>(x, obvs, Jm, rs, rd, out);
}

// Round 12
// 109.915 us; speedup vs baseline: 1.0692x; 1.0692x over previous
//
#include <hip/hip_runtime.h>
#include <math.h>

// B=2, C=1, H=W=2048, RADIUS=1, RK=3; J center plane is zeroed in setup.
// FINAL CONFIGURATION (= R10, best measured: 110.3 us, absmax 0.0078).
// R11's batch-fusion regressed (117.5 us, WRITE +49 MB from NT-store burst
// fragmentation at 12 streams/wave + 18% occupancy) -> reverted.
// Evidence matrix R3-R11: time pinned 110-123 us, invariant to HBM bytes
// (189-498 MB), L2/L3 read service, occupancy (17.5-40%), load width,
// VMEM count (24-30/thr), MLP, batch fusion. Only reproducible win:
// NT stores on THIS unfused 6-stream/wave structure (-5.3%).
namespace {
constexpr int H = 2048;
constexpr int W = 2048;
constexpr int NPIX = H * W;            // 2^22
constexpr int B = 2;
constexpr float DECf = 0.95f;
constexpr float OMDf = 1.0f - 0.95f;
}

using f4 = __attribute__((ext_vector_type(4))) float;

// Structure: 4 px/thread f4 loads, 256 thr/block, 8192 (batch,row,half)
// blocks; XCD-chunked bijective swizzle with batch pair adjacent (J and
// rand_drop fetched from HBM once, sibling hits L2/L3); LDS edge exchange
// for the 6 halo values (no scalar edge loads); NT stores (outputs never
// re-read -> bypass L2/L3 insert).
// Numerics: decision path (tap-sum in tap order, delta_e, exp, compare) in
// f64; EMA observables in f32. Passed 9 rounds, absmax 0.0078 (thr 0.041).
__global__ __launch_bounds__(256, 4) void ising_step_kernel(
    const float* __restrict__ x,      // (B, 2, H, W): s then b
    const float* __restrict__ obvs,   // (B, 4, H, W): e, e2, c, m
    const float* __restrict__ Jm,     // (1, 9, N)
    const float* __restrict__ rs,     // (B, 1, H, W)
    const float* __restrict__ rd,     // (1, 1, H, W)
    float* __restrict__ out)          // state (B,2,N) ++ obvs_out (B,4,N)
{
  __shared__ float lr[3][520];

  const int bid = blockIdx.x;
  const int u   = ((bid & 7) << 10) | (bid >> 3);  // 8 XCDs x 1024 units
  const int bi  = u & 1;                           // batch pair adjacent
  const int pu  = u >> 1;                          // (row, half) in [0,4096)
  const int h   = pu >> 1;                         // [0,2048)
  const int t   = threadIdx.x;
  const int w0b = (pu & 1) << 10;                  // block's first pixel col
  const int w0  = w0b | (t << 2);
  const int n0  = (h << 11) | w0;

  const float* sbase = x + (size_t)bi * 2 * NPIX;
  const int hm = (h - 1) & (H - 1);
  const int hp = (h + 1) & (H - 1);
  const float* rowm = sbase + (size_t)hm * W;
  const float* rowc = sbase + (size_t)h  * W;
  const float* rowp = sbase + (size_t)hp * W;

  // ---- row loads first (LDS writes depend only on these) ----
  const f4 vm = *(const f4*)(rowm + w0);
  const f4 vc = *(const f4*)(rowc + w0);
  const f4 vp = *(const f4*)(rowp + w0);

  // ---- remaining loads issued while LDS exchange proceeds ----
  f4 jv[8];
  #pragma unroll
  for (int k = 0; k < 8; ++k) {
    const int kk = (k < 4) ? k : (k + 1);   // skip zeroed center plane
    jv[k] = *(const f4*)(Jm + (size_t)kk * NPIX + n0);
  }
  const f4 bv  = *(const f4*)(sbase + (size_t)NPIX + n0);
  const float* ob = obvs + (size_t)bi * 4 * NPIX + n0;
  const f4 ev  = *(const f4*)(ob);
  const f4 e2v = *(const f4*)(ob + (size_t)NPIX);
  const f4 cv  = *(const f4*)(ob + 2 * (size_t)NPIX);
  const f4 mv  = *(const f4*)(ob + 3 * (size_t)NPIX);
  const f4 rv  = *(const f4*)(rs + (size_t)bi * NPIX + n0);
  const f4 dv  = *(const f4*)(rd + n0);

  // ---- LDS edge exchange ----
  lr[0][2 * t] = vm.x;  lr[0][2 * t + 3] = vm.w;
  lr[1][2 * t] = vc.x;  lr[1][2 * t + 3] = vc.w;
  lr[2][2 * t] = vp.x;  lr[2][2 * t + 3] = vp.w;
  if (t < 6) {
    const int r    = t >> 1;
    const int side = t & 1;
    const float* rowr = (r == 0) ? rowm : ((r == 1) ? rowc : rowp);
    const int wsrc = side ? ((w0b + 1024) & (W - 1)) : ((w0b - 1) & (W - 1));
    lr[r][side ? 512 : 1] = rowr[wsrc];
  }
  __syncthreads();
  const float Lm = lr[0][2 * t + 1], Rm = lr[0][2 * t + 2];
  const float Lc = lr[1][2 * t + 1], Rc = lr[1][2 * t + 2];
  const float Lp = lr[2][2 * t + 1], Rp = lr[2][2 * t + 2];

  const float am[6] = {Lm, vm.x, vm.y, vm.z, vm.w, Rm};
  const float ac[6] = {Lc, vc.x, vc.y, vc.z, vc.w, Rc};
  const float ap[6] = {Lp, vp.x, vp.y, vp.z, vp.w, Rp};

  const float bq[4]  = {bv.x, bv.y, bv.z, bv.w};
  const float eq[4]  = {ev.x, ev.y, ev.z, ev.w};
  const float e2q[4] = {e2v.x, e2v.y, e2v.z, e2v.w};
  const float cq[4]  = {cv.x, cv.y, cv.z, cv.w};
  const float mq[4]  = {mv.x, mv.y, mv.z, mv.w};
  const float rsq[4] = {rv.x, rv.y, rv.z, rv.w};
  const float rdq[4] = {dv.x, dv.y, dv.z, dv.w};

  float so[4], eo[4], e2o[4], co[4], mo[4];
  #pragma unroll
  for (int tt = 0; tt < 4; ++tt) {
    // decision-critical path in f64, reference tap order
    const double sum =
        (double)jv[0][tt] * am[tt]     + (double)jv[1][tt] * am[tt + 1] +
        (double)jv[2][tt] * am[tt + 2] + (double)jv[3][tt] * ac[tt]     +
        (double)jv[4][tt] * ac[tt + 2] + (double)jv[5][tt] * ap[tt]     +
        (double)jv[6][tt] * ap[tt + 1] + (double)jv[7][tt] * ap[tt + 2];
    const float sf  = ac[tt + 1];
    const double s  = (double)sf;
    const double de = 2.0 * s * sum;
    const double p  = (de <= 0.0) ? 1.0 : exp(-de * (double)bq[tt]);
    const bool acc  = ((double)rsq[tt] < p) && (rdq[tt] > 0.5f);
    // observables in f32
    const float E   = (float)(-s * sum);
    const float bf  = bq[tt];
    const float en  = DECf * eq[tt]  + OMDf * E;
    const float e2n = DECf * e2q[tt] + OMDf * E * E;
    const float cn  = DECf * cq[tt]  + OMDf * (e2n - en * en) * bf * bf;
    const float mn  = DECf * mq[tt]  + OMDf * sf;
    so[tt]  = acc ? -sf : sf;
    eo[tt]  = en;
    e2o[tt] = e2n;
    co[tt]  = cn;
    mo[tt]  = mn;
  }

  // ---- outputs: nontemporal (never re-read; don't claim L2/L3) ----
  float* st = out + (size_t)bi * 2 * NPIX;
  float* oo = out + (size_t)B * 2 * NPIX + (size_t)bi * 4 * NPIX;
  __builtin_nontemporal_store((f4){so[0], so[1], so[2], so[3]}, (f4*)(st + n0));
  __builtin_nontemporal_store(bv, (f4*)(st + (size_t)NPIX + n0));
  __builtin_nontemporal_store((f4){eo[0], eo[1], eo[2], eo[3]}, (f4*)(oo + n0));
  __builtin_nontemporal_store((f4){e2o[0], e2o[1], e2o[2], e2o[3]},
                              (f4*)(oo + (size_t)NPIX + n0));
  __builtin_nontemporal_store((f4){co[0], co[1], co[2], co[3]},
                              (f4*)(oo + 2 * (size_t)NPIX + n0));
  __builtin_nontemporal_store((f4){mo[0], mo[1], mo[2], mo[3]},
                              (f4*)(oo + 3 * (size_t)NPIX + n0));
}

extern "C" void kernel_launch(void* const* d_in, const int* in_sizes, int n_in,
                              void* d_out, int out_size, void* d_ws, size_t ws_size,
                              hipStream_t stream) {
  const float* x    = (const float*)d_in[0];
  const float* obvs = (const float*)d_in[1];
  const float* Jm   = (const float*)d_in[2];
  const float* rs   = (const float*)d_in[3];
  const float* rd   = (const float*)d_in[4];
  float* out = (float*)d_out;

  constexpr int grid = B * H * 2;   // 8192 (batch, row, half) units
  ising_step_kernel<<<grid, 256, 0, stream>>>(x, obvs, Jm, rs, rd, out);
}